// Round 13
// baseline (199.027 us; speedup 1.0000x reference)
//
#include <hip/hip_runtime.h>
#include <hip/hip_bf16.h>

// Problem constants
#define BATCH 8
#define CCH   256
#define NPOS  4096
#define CQK   32
#define LOG2E 1.4426950408889634f

// ---------------------------------------------------------------------------
// Fast exp path (R11-verified: −11 pts VALUBusy vs __expf).
// ---------------------------------------------------------------------------
#if defined(__has_builtin)
#if __has_builtin(__builtin_amdgcn_exp2f)
#define HAVE_EXP2 1
#endif
#endif
#ifndef HAVE_EXP2
#define HAVE_EXP2 0
#endif

#if HAVE_EXP2
#define KSC_W LOG2E                    // pre-scale Wk/bk by log2e at prep
__device__ inline float fast_exp(float x) { return __builtin_amdgcn_exp2f(x); }
#else
#define KSC_W 1.0f
__device__ inline float fast_exp(float x) { return __expf(x); }
#endif

typedef __attribute__((ext_vector_type(8))) short short8;   // 8 bf16 = 4 VGPRs (MFMA A/B frag)
typedef __attribute__((ext_vector_type(4))) float f32x4;    // MFMA C/D frag

__device__ inline unsigned short f2b(float f) {
    __hip_bfloat16 h = __float2bfloat16(f);
    return *reinterpret_cast<unsigned short*>(&h);
}

// ---------------------------------------------------------------------------
// Fragment-block swizzled layouts (unchanged, harness-verified).
// ---------------------------------------------------------------------------
__device__ inline size_t qk_addr(int b, int n, int c) {
    return ((((size_t)b * 256 + (n >> 4)) * 4 + (c >> 3)) * 16 + (n & 15)) * 8 + (c & 7);
}
__device__ inline size_t v_addr(int b, int c, int j) {
    return (((((size_t)b * 128 + (j >> 5)) * 16 + (c >> 4)) * 4 + ((j >> 3) & 3)) * 16 + (c & 15)) * 8 + (j & 7);
}
__device__ inline size_t wsw_addr(int og, int c, int ol) {
    return ((size_t)(og * 8 + (c >> 5))) * 512 + (((c >> 3) & 3) * 16 + ol) * 8 + (c & 7);
}

// ---------------------------------------------------------------------------
// Kernel 0: prep_w (unchanged from R12).
// ---------------------------------------------------------------------------
__global__ __launch_bounds__(256, 4)
void prep_w_kernel(const float* __restrict__ Wq, const float* __restrict__ Wk,
                   const float* __restrict__ Wv, const float* __restrict__ Wf,
                   unsigned short* __restrict__ wsw)
{
    const int og = blockIdx.x;           // 0..35
    const int t  = threadIdx.x;
    const float* src; int orow; float scl = 1.f;
    if (og < 2)       { src = Wq; orow = og * 16; }
    else if (og < 4)  { src = Wk; orow = (og - 2) * 16; scl = KSC_W; }
    else if (og < 20) { src = Wv; orow = (og - 4) * 16; }
    else              { src = Wf; orow = (og - 20) * 16; }
    #pragma unroll
    for (int e = 0; e < 16; ++e) {
        int idx = t + e * 256;
        int ol = idx >> 8, c = idx & 255;
        wsw[wsw_addr(og, c, ol)] = f2b(src[(orow + ol) * 256 + c] * scl);
    }
}

// ---------------------------------------------------------------------------
// Kernel 1: fused transpose + QKV projection (unchanged from R12).
// ---------------------------------------------------------------------------
__global__ __launch_bounds__(512, 2)
void qkv_kernel(const float* __restrict__ x,
                const unsigned short* __restrict__ wsw,
                const float* __restrict__ bq, const float* __restrict__ bk,
                const float* __restrict__ bv,
                unsigned short* __restrict__ qb, unsigned short* __restrict__ kb,
                unsigned short* __restrict__ vb)
{
    __shared__ __align__(16) unsigned short xl[64 * 280];   // [n][c pad 280] = 35840 B

    const int nt   = blockIdx.x;
    const int b    = blockIdx.y;
    const int t    = threadIdx.x;
    const int w    = t >> 6;
    const int lane = t & 63;
    const int q    = lane >> 4;
    const int ln   = lane & 15;
    const int lofs = (q * 16 + ln) * 8;
    const int wq   = w & 3;
    const int ith  = w >> 2;

    {
        const int c  = t & 255;
        const int nb = (t >> 8) * 4;
        const float* xb = x + ((size_t)(b * 256 + c)) * 4096 + nt * 64;
        #pragma unroll
        for (int e = 0; e < 8; ++e) {
            const int n = nb + e * 8;
            float4 v = *(const float4*)(xb + n);
            xl[(n + 0) * 280 + c] = f2b(v.x);
            xl[(n + 1) * 280 + c] = f2b(v.y);
            xl[(n + 2) * 280 + c] = f2b(v.z);
            xl[(n + 3) * 280 + c] = f2b(v.w);
        }
    }
    __syncthreads();

    short8 wqk[8];
    #pragma unroll
    for (int kk = 0; kk < 8; ++kk)
        wqk[kk] = *(const short8*)(wsw + (size_t)(wq * 8 + kk) * 512 + lofs);
    const float* bias = (wq < 2) ? bq : bk;
    const float ksc = (wq < 2) ? 1.f : KSC_W;
    const int cb16 = (wq & 1) * 16;
    const float b0 = bias[cb16 + q * 4 + 0] * ksc;
    const float b1 = bias[cb16 + q * 4 + 1] * ksc;
    const float b2 = bias[cb16 + q * 4 + 2] * ksc;
    const float b3 = bias[cb16 + q * 4 + 3] * ksc;
    unsigned short* dst = (wq < 2) ? qb : kb;

    #pragma unroll
    for (int itl = 0; itl < 2; ++itl) {
        const int it = ith * 2 + itl;
        short8 xf[8];
        #pragma unroll
        for (int kk = 0; kk < 8; ++kk)
            xf[kk] = *(const short8*)&xl[(it * 16 + ln) * 280 + kk * 32 + q * 8];

        {
            f32x4 acc = {b0, b1, b2, b3};
            #pragma unroll
            for (int kk = 0; kk < 8; ++kk)
                acc = __builtin_amdgcn_mfma_f32_16x16x32_bf16(wqk[kk], xf[kk], acc, 0, 0, 0);
            ushort4 s = {f2b(acc[0]), f2b(acc[1]), f2b(acc[2]), f2b(acc[3])};
            *(ushort4*)(dst + qk_addr(b, nt * 64 + it * 16 + ln, cb16 + q * 4)) = s;
        }

        #pragma unroll
        for (int oq = 0; oq < 4; ++oq) {
            const int c  = wq * 64 + oq * 16 + ln;
            const float bb = bv[c];
            f32x4 acc = {bb, bb, bb, bb};
            const int og = 4 + wq * 4 + oq;
            #pragma unroll
            for (int kk = 0; kk < 8; ++kk) {
                short8 bfr = *(const short8*)(wsw + (size_t)(og * 8 + kk) * 512 + lofs);
                acc = __builtin_amdgcn_mfma_f32_16x16x32_bf16(xf[kk], bfr, acc, 0, 0, 0);
            }
            ushort4 s = {f2b(acc[0]), f2b(acc[1]), f2b(acc[2]), f2b(acc[3])};
            *(ushort4*)(vb + v_addr(b, c, nt * 64 + it * 16 + q * 4)) = s;
        }
    }
}

// ---------------------------------------------------------------------------
// Kernel 2: fused flash attention + output projection — R13: balanced roles.
// R12 doubled occupancy (94.2 µs) but waves 0-3 carried ALL of S/exp/P-write
// (4 MFMA + 16 exp + 16 writes) while waves 4-7 idled at the barrier.
// Now wave w = (row-tile wr=w&3, j-half jh=w>>2): each wave computes S for
// its row-tile over its 2 j-column-tiles -> 2 S-MFMA + 8 exp + 8 P-writes
// per wave, per-iter critical path balanced.  Row sums: two partials
// (lred2[jh][row]) summed in the epilogue.  PV/layouts/barrier unchanged.
// ---------------------------------------------------------------------------
__global__ __launch_bounds__(512, 4)
void attn_kernel(const unsigned short* __restrict__ qb,
                 const unsigned short* __restrict__ kb,
                 const unsigned short* __restrict__ vb,
                 const unsigned short* __restrict__ wsw,
                 const float* __restrict__ bfb, float* __restrict__ out)
{
    // shbuf aliases: main loop P tiles [2][64][72] (9216 shorts),
    //                epilogue O_n      [64][264]   (16896 shorts)
    __shared__ __align__(16) unsigned short shbuf[64 * 264];
    __shared__ float lred2[2][64];

    const int bid  = blockIdx.x;
    const int b    = bid & 7;                    // XCD swizzle
    const int i0   = (bid >> 3) * 64;
    const int t    = threadIdx.x;                // 0..511
    const int w    = t >> 6;                     // 0..7
    const int lane = t & 63;
    const int quad = lane >> 4;
    const int ln   = lane & 15;
    const int lofs = (quad * 16 + ln) * 8;
    const int wr   = w & 3;                      // row-tile
    const int jh   = w >> 2;                     // j-half (2 j-tiles each)

    const unsigned short* kbase = kb + (size_t)b * 256 * 512;
    const unsigned short* vbase = vb + (size_t)b * 128 * 8192;

    const short8 qfrag = *(const short8*)(qb + (((size_t)b * 256 + ((i0 + wr * 16) >> 4)) * 512) + lofs);

    // K fragments for this wave's 2 j-tiles (prefetch depth 1 iter)
    short8 kf[2];
    #pragma unroll
    for (int jcl = 0; jcl < 2; ++jcl)
        kf[jcl] = *(const short8*)(kbase + (size_t)(jh * 2 + jcl) * 512 + lofs);

    f32x4 acc[4][2];                             // [i-tile][c-chunk of 32]
    #pragma unroll
    for (int it = 0; it < 4; ++it)
        #pragma unroll
        for (int cc = 0; cc < 2; ++cc) acc[it][cc] = (f32x4){0.f, 0.f, 0.f, 0.f};
    float accl[4] = {0.f, 0.f, 0.f, 0.f};        // partial row sums (this j-half)

    int pb = 0;
    for (int j0 = 0; j0 < 4096; j0 += 64, pb ^= 1) {
        // ---- V for THIS iter (single-buffered; TLP hides latency) ----
        short8 vf[2][2];
        const unsigned short* vt = vbase + (size_t)(j0 >> 5) * 8192;
        #pragma unroll
        for (int cc = 0; cc < 2; ++cc) {
            vf[cc][0] = *(const short8*)(vt + (w * 2 + cc) * 512 + lofs);
            vf[cc][1] = *(const short8*)(vt + 8192 + (w * 2 + cc) * 512 + lofs);
        }
        // ---- prefetch next-iter K (this wave's 2 tiles) ----
        const int jn = (j0 + 64) & 4095;
        short8 kf_n[2];
        #pragma unroll
        for (int jcl = 0; jcl < 2; ++jcl)
            kf_n[jcl] = *(const short8*)(kbase + ((size_t)((jn >> 4) + jh * 2 + jcl) * 512) + lofs);
        // ---- S = Q K^T for this wave's row-tile x 2 j-tiles ----
        #pragma unroll
        for (int jcl = 0; jcl < 2; ++jcl) {
            const int jc = jh * 2 + jcl;
            f32x4 s = __builtin_amdgcn_mfma_f32_16x16x32_bf16(qfrag, kf[jcl],
                       (f32x4){0.f, 0.f, 0.f, 0.f}, 0, 0, 0);
            #pragma unroll
            for (int r = 0; r < 4; ++r) {
                float p = fast_exp(s[r]);
                accl[r] += p;
                shbuf[((size_t)(pb * 64 + wr * 16 + quad * 4 + r)) * 72 + jc * 16 + ln] = f2b(p);
            }
        }
        __syncthreads();
        // ---- O += P V : all 8 waves, 16 MFMAs each ----
        #pragma unroll
        for (int it = 0; it < 4; ++it) {
            const short8 pf0 = *(const short8*)&shbuf[((size_t)(pb * 64 + it * 16 + ln)) * 72 + quad * 8];
            const short8 pf1 = *(const short8*)&shbuf[((size_t)(pb * 64 + it * 16 + ln)) * 72 + 32 + quad * 8];
            #pragma unroll
            for (int cc = 0; cc < 2; ++cc) {
                acc[it][cc] = __builtin_amdgcn_mfma_f32_16x16x32_bf16(pf0, vf[cc][0], acc[it][cc], 0, 0, 0);
                acc[it][cc] = __builtin_amdgcn_mfma_f32_16x16x32_bf16(pf1, vf[cc][1], acc[it][cc], 0, 0, 0);
            }
        }
        #pragma unroll
        for (int jcl = 0; jcl < 2; ++jcl) kf[jcl] = kf_n[jcl];
    }

    // ---- row sums: reduce across ln within quad; two partials per row ----
    #pragma unroll
    for (int r = 0; r < 4; ++r) {
        float v = accl[r];
        v += __shfl_xor(v, 1, 16);
        v += __shfl_xor(v, 2, 16);
        v += __shfl_xor(v, 4, 16);
        v += __shfl_xor(v, 8, 16);
        if (ln == 0) lred2[jh][wr * 16 + quad * 4 + r] = v;
    }
    __syncthreads();   // also orders: last P reads before O_n overwrites shbuf

    // ---- epilogue A: normalize O, write bf16 to LDS [i][c] (stride 264) ----
    #pragma unroll
    for (int it = 0; it < 4; ++it) {
        float linv[4];
        #pragma unroll
        for (int r = 0; r < 4; ++r) {
            const int row = it * 16 + quad * 4 + r;
            linv[r] = 1.f / (lred2[0][row] + lred2[1][row]);
        }
        #pragma unroll
        for (int cc = 0; cc < 2; ++cc) {
            const int c = w * 32 + cc * 16 + ln;
            #pragma unroll
            for (int r = 0; r < 4; ++r)
                shbuf[((size_t)(it * 16 + quad * 4 + r)) * 264 + c] = f2b(acc[it][cc][r] * linv[r]);
        }
    }
    __syncthreads();

    // ---- epilogue B: out = Wf * O_n + bf, each wave owns o-chunk w*32 ----
    #pragma unroll
    for (int it = 0; it < 4; ++it) {
        short8 af[8];
        #pragma unroll
        for (int kk = 0; kk < 8; ++kk)
            af[kk] = *(const short8*)&shbuf[((size_t)(it * 16 + ln)) * 264 + kk * 32 + quad * 8];
        #pragma unroll
        for (int oq = 0; oq < 2; ++oq) {
            const int o  = w * 32 + oq * 16 + ln;
            const int og = 20 + w * 2 + oq;
            f32x4 pa = {0.f, 0.f, 0.f, 0.f};
            #pragma unroll
            for (int kk = 0; kk < 8; ++kk) {
                short8 bfr = *(const short8*)(wsw + (size_t)(og * 8 + kk) * 512 + lofs);
                pa = __builtin_amdgcn_mfma_f32_16x16x32_bf16(af[kk], bfr, pa, 0, 0, 0);
            }
            const float bias = bfb[o];
            float4 s = {pa[0] + bias, pa[1] + bias, pa[2] + bias, pa[3] + bias};
            *(float4*)(out + (size_t)(b * 256 + o) * 4096 + i0 + it * 16 + quad * 4) = s;
        }
    }
}

// ---------------------------------------------------------------------------
extern "C" void kernel_launch(void* const* d_in, const int* in_sizes, int n_in,
                              void* d_out, int out_size, void* d_ws, size_t ws_size,
                              hipStream_t stream)
{
    const float* x  = (const float*)d_in[0];
    const float* Wq = (const float*)d_in[1];
    const float* bq = (const float*)d_in[2];
    const float* Wk = (const float*)d_in[3];
    const float* bk = (const float*)d_in[4];
    const float* Wv = (const float*)d_in[5];
    const float* bv = (const float*)d_in[6];
    const float* Wf = (const float*)d_in[7];
    const float* bf = (const float*)d_in[8];
    float* out = (float*)d_out;

    // workspace (shorts): qb, kb, vb, wsw
    unsigned short* qb  = (unsigned short*)d_ws;                  // 8*4096*32
    unsigned short* kb  = qb + (size_t)BATCH * NPOS * CQK;
    unsigned short* vb  = kb + (size_t)BATCH * NPOS * CQK;        // 8*256*4096
    unsigned short* wsw = vb + (size_t)BATCH * CCH * NPOS;        // 36*8*512

    prep_w_kernel<<<36, 256, 0, stream>>>(Wq, Wk, Wv, Wf, wsw);
    qkv_kernel<<<dim3(64, 8), 512, 0, stream>>>(x, wsw, bq, bk, bv, qb, kb, vb);
    attn_kernel<<<512, 512, 0, stream>>>(qb, kb, vb, wsw, bf, out);
}

// Round 14
// 198.055 us; speedup vs baseline: 1.0049x; 1.0049x over previous
//
#include <hip/hip_runtime.h>
#include <hip/hip_bf16.h>

// Problem constants
#define BATCH 8
#define CCH   256
#define NPOS  4096
#define CQK   32
#define LOG2E 1.4426950408889634f

// ---------------------------------------------------------------------------
// Fast exp path (R11-verified: −11 pts VALUBusy vs __expf).
// ---------------------------------------------------------------------------
#if defined(__has_builtin)
#if __has_builtin(__builtin_amdgcn_exp2f)
#define HAVE_EXP2 1
#endif
#endif
#ifndef HAVE_EXP2
#define HAVE_EXP2 0
#endif

#if HAVE_EXP2
#define KSC_W LOG2E                    // pre-scale Wk/bk by log2e at prep
__device__ inline float fast_exp(float x) { return __builtin_amdgcn_exp2f(x); }
#else
#define KSC_W 1.0f
__device__ inline float fast_exp(float x) { return __expf(x); }
#endif

typedef __attribute__((ext_vector_type(8))) short short8;   // 8 bf16 = 4 VGPRs (MFMA A/B frag)
typedef __attribute__((ext_vector_type(4))) float f32x4;    // MFMA C/D frag

__device__ inline unsigned short f2b(float f) {
    __hip_bfloat16 h = __float2bfloat16(f);
    return *reinterpret_cast<unsigned short*>(&h);
}

// ---------------------------------------------------------------------------
// Fragment-block swizzled layouts (unchanged, harness-verified).
// ---------------------------------------------------------------------------
__device__ inline size_t qk_addr(int b, int n, int c) {
    return ((((size_t)b * 256 + (n >> 4)) * 4 + (c >> 3)) * 16 + (n & 15)) * 8 + (c & 7);
}
__device__ inline size_t v_addr(int b, int c, int j) {
    return (((((size_t)b * 128 + (j >> 5)) * 16 + (c >> 4)) * 4 + ((j >> 3) & 3)) * 16 + (c & 15)) * 8 + (j & 7);
}
__device__ inline size_t wsw_addr(int og, int c, int ol) {
    return ((size_t)(og * 8 + (c >> 5))) * 512 + (((c >> 3) & 3) * 16 + ol) * 8 + (c & 7);
}

// ---------------------------------------------------------------------------
// Kernel 0: prep_w (unchanged from R12).
// ---------------------------------------------------------------------------
__global__ __launch_bounds__(256, 4)
void prep_w_kernel(const float* __restrict__ Wq, const float* __restrict__ Wk,
                   const float* __restrict__ Wv, const float* __restrict__ Wf,
                   unsigned short* __restrict__ wsw)
{
    const int og = blockIdx.x;           // 0..35
    const int t  = threadIdx.x;
    const float* src; int orow; float scl = 1.f;
    if (og < 2)       { src = Wq; orow = og * 16; }
    else if (og < 4)  { src = Wk; orow = (og - 2) * 16; scl = KSC_W; }
    else if (og < 20) { src = Wv; orow = (og - 4) * 16; }
    else              { src = Wf; orow = (og - 20) * 16; }
    #pragma unroll
    for (int e = 0; e < 16; ++e) {
        int idx = t + e * 256;
        int ol = idx >> 8, c = idx & 255;
        wsw[wsw_addr(og, c, ol)] = f2b(src[(orow + ol) * 256 + c] * scl);
    }
}

// ---------------------------------------------------------------------------
// Kernel 1: fused transpose + QKV projection (unchanged from R12).
// ---------------------------------------------------------------------------
__global__ __launch_bounds__(512, 2)
void qkv_kernel(const float* __restrict__ x,
                const unsigned short* __restrict__ wsw,
                const float* __restrict__ bq, const float* __restrict__ bk,
                const float* __restrict__ bv,
                unsigned short* __restrict__ qb, unsigned short* __restrict__ kb,
                unsigned short* __restrict__ vb)
{
    __shared__ __align__(16) unsigned short xl[64 * 280];   // [n][c pad 280] = 35840 B

    const int nt   = blockIdx.x;
    const int b    = blockIdx.y;
    const int t    = threadIdx.x;
    const int w    = t >> 6;
    const int lane = t & 63;
    const int q    = lane >> 4;
    const int ln   = lane & 15;
    const int lofs = (q * 16 + ln) * 8;
    const int wq   = w & 3;
    const int ith  = w >> 2;

    {
        const int c  = t & 255;
        const int nb = (t >> 8) * 4;
        const float* xb = x + ((size_t)(b * 256 + c)) * 4096 + nt * 64;
        #pragma unroll
        for (int e = 0; e < 8; ++e) {
            const int n = nb + e * 8;
            float4 v = *(const float4*)(xb + n);
            xl[(n + 0) * 280 + c] = f2b(v.x);
            xl[(n + 1) * 280 + c] = f2b(v.y);
            xl[(n + 2) * 280 + c] = f2b(v.z);
            xl[(n + 3) * 280 + c] = f2b(v.w);
        }
    }
    __syncthreads();

    short8 wqk[8];
    #pragma unroll
    for (int kk = 0; kk < 8; ++kk)
        wqk[kk] = *(const short8*)(wsw + (size_t)(wq * 8 + kk) * 512 + lofs);
    const float* bias = (wq < 2) ? bq : bk;
    const float ksc = (wq < 2) ? 1.f : KSC_W;
    const int cb16 = (wq & 1) * 16;
    const float b0 = bias[cb16 + q * 4 + 0] * ksc;
    const float b1 = bias[cb16 + q * 4 + 1] * ksc;
    const float b2 = bias[cb16 + q * 4 + 2] * ksc;
    const float b3 = bias[cb16 + q * 4 + 3] * ksc;
    unsigned short* dst = (wq < 2) ? qb : kb;

    #pragma unroll
    for (int itl = 0; itl < 2; ++itl) {
        const int it = ith * 2 + itl;
        short8 xf[8];
        #pragma unroll
        for (int kk = 0; kk < 8; ++kk)
            xf[kk] = *(const short8*)&xl[(it * 16 + ln) * 280 + kk * 32 + q * 8];

        {
            f32x4 acc = {b0, b1, b2, b3};
            #pragma unroll
            for (int kk = 0; kk < 8; ++kk)
                acc = __builtin_amdgcn_mfma_f32_16x16x32_bf16(wqk[kk], xf[kk], acc, 0, 0, 0);
            ushort4 s = {f2b(acc[0]), f2b(acc[1]), f2b(acc[2]), f2b(acc[3])};
            *(ushort4*)(dst + qk_addr(b, nt * 64 + it * 16 + ln, cb16 + q * 4)) = s;
        }

        #pragma unroll
        for (int oq = 0; oq < 4; ++oq) {
            const int c  = wq * 64 + oq * 16 + ln;
            const float bb = bv[c];
            f32x4 acc = {bb, bb, bb, bb};
            const int og = 4 + wq * 4 + oq;
            #pragma unroll
            for (int kk = 0; kk < 8; ++kk) {
                short8 bfr = *(const short8*)(wsw + (size_t)(og * 8 + kk) * 512 + lofs);
                acc = __builtin_amdgcn_mfma_f32_16x16x32_bf16(xf[kk], bfr, acc, 0, 0, 0);
            }
            ushort4 s = {f2b(acc[0]), f2b(acc[1]), f2b(acc[2]), f2b(acc[3])};
            *(ushort4*)(vb + v_addr(b, c, nt * 64 + it * 16 + q * 4)) = s;
        }
    }
}

// ---------------------------------------------------------------------------
// Kernel 2: fused flash attention + output projection — R14 = R12 (measured
// best, 94.2 µs: 8-wave blocks, heavy/light role split — waves 0-3 S/exp/P,
// all 8 PV; the asymmetry is absorbed by SIMD co-scheduling, R13 proved
// balancing hurts) + T5 s_setprio around the PV MFMA cluster.  Mechanism:
// the 2 co-resident blocks drift out of phase, so PV waves (MFMA) compete
// with the other block's exp (VALU); setprio(1) favors the MFMA burst
// (m191: +4-7% on attn with cross-block role diversity).
// ---------------------------------------------------------------------------
__global__ __launch_bounds__(512, 4)
void attn_kernel(const unsigned short* __restrict__ qb,
                 const unsigned short* __restrict__ kb,
                 const unsigned short* __restrict__ vb,
                 const unsigned short* __restrict__ wsw,
                 const float* __restrict__ bfb, float* __restrict__ out)
{
    // shbuf aliases: main loop P tiles [2][64][72] (9216 shorts),
    //                epilogue O_n      [64][264]   (16896 shorts)
    __shared__ __align__(16) unsigned short shbuf[64 * 264];
    __shared__ float lred[64];

    const int bid  = blockIdx.x;
    const int b    = bid & 7;                    // XCD swizzle
    const int i0   = (bid >> 3) * 64;
    const int t    = threadIdx.x;                // 0..511
    const int w    = t >> 6;                     // 0..7
    const int lane = t & 63;
    const int quad = lane >> 4;
    const int ln   = lane & 15;
    const int lofs = (quad * 16 + ln) * 8;

    const unsigned short* kbase = kb + (size_t)b * 256 * 512;
    const unsigned short* vbase = vb + (size_t)b * 128 * 8192;

    // S-role (waves 0-3): rows w*16..w*16+15
    short8 qfrag = {};
    short8 kf[4];
    if (w < 4) {
        qfrag = *(const short8*)(qb + (((size_t)b * 256 + ((i0 + w * 16) >> 4)) * 512) + lofs);
        #pragma unroll
        for (int jc = 0; jc < 4; ++jc)
            kf[jc] = *(const short8*)(kbase + (size_t)jc * 512 + lofs);
    }

    f32x4 acc[4][2];                             // [i-tile][c-chunk of 32: 2 tiles]
    #pragma unroll
    for (int it = 0; it < 4; ++it)
        #pragma unroll
        for (int cc = 0; cc < 2; ++cc) acc[it][cc] = (f32x4){0.f, 0.f, 0.f, 0.f};
    float accl[4] = {0.f, 0.f, 0.f, 0.f};

    int pb = 0;
    for (int j0 = 0; j0 < 4096; j0 += 64, pb ^= 1) {
        // ---- V for THIS iter (single-buffered; used after S/exp/barrier) ----
        short8 vf[2][2];
        const unsigned short* vt = vbase + (size_t)(j0 >> 5) * 8192;
        #pragma unroll
        for (int cc = 0; cc < 2; ++cc) {
            vf[cc][0] = *(const short8*)(vt + (w * 2 + cc) * 512 + lofs);
            vf[cc][1] = *(const short8*)(vt + 8192 + (w * 2 + cc) * 512 + lofs);
        }
        short8 kf_n[4];
        if (w < 4) {
            // ---- prefetch next-iter K ----
            const int jn = (j0 + 64) & 4095;
            #pragma unroll
            for (int jc = 0; jc < 4; ++jc)
                kf_n[jc] = *(const short8*)(kbase + ((size_t)((jn >> 4) + jc) * 512) + lofs);
            // ---- S = Q K^T with resident K ----
            f32x4 s[4];
            #pragma unroll
            for (int jc = 0; jc < 4; ++jc)
                s[jc] = __builtin_amdgcn_mfma_f32_16x16x32_bf16(qfrag, kf[jc],
                         (f32x4){0.f, 0.f, 0.f, 0.f}, 0, 0, 0);
            // ---- P = exp(S); row sums; write block-shared P ----
            #pragma unroll
            for (int jc = 0; jc < 4; ++jc) {
                #pragma unroll
                for (int r = 0; r < 4; ++r) {
                    float p = fast_exp(s[jc][r]);
                    accl[r] += p;
                    shbuf[((size_t)(pb * 64 + w * 16 + quad * 4 + r)) * 72 + jc * 16 + ln] = f2b(p);
                }
            }
        }
        __syncthreads();
        // ---- O += P V : all 8 waves, 16 MFMAs each (T5: prio up) ----
        __builtin_amdgcn_s_setprio(1);
        #pragma unroll
        for (int it = 0; it < 4; ++it) {
            const short8 pf0 = *(const short8*)&shbuf[((size_t)(pb * 64 + it * 16 + ln)) * 72 + quad * 8];
            const short8 pf1 = *(const short8*)&shbuf[((size_t)(pb * 64 + it * 16 + ln)) * 72 + 32 + quad * 8];
            #pragma unroll
            for (int cc = 0; cc < 2; ++cc) {
                acc[it][cc] = __builtin_amdgcn_mfma_f32_16x16x32_bf16(pf0, vf[cc][0], acc[it][cc], 0, 0, 0);
                acc[it][cc] = __builtin_amdgcn_mfma_f32_16x16x32_bf16(pf1, vf[cc][1], acc[it][cc], 0, 0, 0);
            }
        }
        __builtin_amdgcn_s_setprio(0);
        if (w < 4) {
            #pragma unroll
            for (int jc = 0; jc < 4; ++jc) kf[jc] = kf_n[jc];
        }
    }

    // ---- row sums (waves 0-3 own rows) ----
    if (w < 4) {
        #pragma unroll
        for (int r = 0; r < 4; ++r) {
            float v = accl[r];
            v += __shfl_xor(v, 1, 16);
            v += __shfl_xor(v, 2, 16);
            v += __shfl_xor(v, 4, 16);
            v += __shfl_xor(v, 8, 16);
            if (ln == 0) lred[w * 16 + quad * 4 + r] = v;
        }
    }
    __syncthreads();   // also orders: last P reads before O_n overwrites shbuf

    // ---- epilogue A: normalize O, write bf16 to LDS [i][c] (stride 264) ----
    #pragma unroll
    for (int it = 0; it < 4; ++it) {
        float linv[4];
        #pragma unroll
        for (int r = 0; r < 4; ++r) linv[r] = 1.f / lred[it * 16 + quad * 4 + r];
        #pragma unroll
        for (int cc = 0; cc < 2; ++cc) {
            const int c = w * 32 + cc * 16 + ln;
            #pragma unroll
            for (int r = 0; r < 4; ++r)
                shbuf[((size_t)(it * 16 + quad * 4 + r)) * 264 + c] = f2b(acc[it][cc][r] * linv[r]);
        }
    }
    __syncthreads();

    // ---- epilogue B: out = Wf * O_n + bf, each wave owns o-chunk w*32 ----
    #pragma unroll
    for (int it = 0; it < 4; ++it) {
        short8 af[8];
        #pragma unroll
        for (int kk = 0; kk < 8; ++kk)
            af[kk] = *(const short8*)&shbuf[((size_t)(it * 16 + ln)) * 264 + kk * 32 + quad * 8];
        #pragma unroll
        for (int oq = 0; oq < 2; ++oq) {
            const int o  = w * 32 + oq * 16 + ln;
            const int og = 20 + w * 2 + oq;
            f32x4 pa = {0.f, 0.f, 0.f, 0.f};
            #pragma unroll
            for (int kk = 0; kk < 8; ++kk) {
                short8 bfr = *(const short8*)(wsw + (size_t)(og * 8 + kk) * 512 + lofs);
                pa = __builtin_amdgcn_mfma_f32_16x16x32_bf16(af[kk], bfr, pa, 0, 0, 0);
            }
            const float bias = bfb[o];
            float4 s = {pa[0] + bias, pa[1] + bias, pa[2] + bias, pa[3] + bias};
            *(float4*)(out + (size_t)(b * 256 + o) * 4096 + i0 + it * 16 + quad * 4) = s;
        }
    }
}

// ---------------------------------------------------------------------------
extern "C" void kernel_launch(void* const* d_in, const int* in_sizes, int n_in,
                              void* d_out, int out_size, void* d_ws, size_t ws_size,
                              hipStream_t stream)
{
    const float* x  = (const float*)d_in[0];
    const float* Wq = (const float*)d_in[1];
    const float* bq = (const float*)d_in[2];
    const float* Wk = (const float*)d_in[3];
    const float* bk = (const float*)d_in[4];
    const float* Wv = (const float*)d_in[5];
    const float* bv = (const float*)d_in[6];
    const float* Wf = (const float*)d_in[7];
    const float* bf = (const float*)d_in[8];
    float* out = (float*)d_out;

    // workspace (shorts): qb, kb, vb, wsw
    unsigned short* qb  = (unsigned short*)d_ws;                  // 8*4096*32
    unsigned short* kb  = qb + (size_t)BATCH * NPOS * CQK;
    unsigned short* vb  = kb + (size_t)BATCH * NPOS * CQK;        // 8*256*4096
    unsigned short* wsw = vb + (size_t)BATCH * CCH * NPOS;        // 36*8*512

    prep_w_kernel<<<36, 256, 0, stream>>>(Wq, Wk, Wv, Wf, wsw);
    qkv_kernel<<<dim3(64, 8), 512, 0, stream>>>(x, wsw, bq, bk, bv, qb, kb, vb);
    attn_kernel<<<512, 512, 0, stream>>>(qb, kb, vb, wsw, bf, out);
}